// Round 6
// baseline (1382.107 us; speedup 1.0000x reference)
//
#include <hip/hip_runtime.h>

// ---- problem constants ----
constexpr int B_  = 128;
constexpr int T_  = 24;
constexpr int E_  = 512;
constexpr int H_  = 512;
constexpr int V_  = 10000;
constexpr int VP_ = 10112;  // V padded to 128-multiple for logits tiling
constexpr int G4  = 2048;   // 4*H
constexpr int TP1 = 25;     // T+1

typedef __attribute__((ext_vector_type(8))) short bf16x8;   // 8 bf16 = 4 VGPR
typedef __attribute__((ext_vector_type(4))) short short4v;  // 4 bf16 = 8 B
typedef __attribute__((ext_vector_type(4))) float f32x4;

#define MFMA_16x16x32_BF16(a, b, c) __builtin_amdgcn_mfma_f32_16x16x32_bf16((a), (b), (c), 0, 0, 0)

// fp32 -> bf16 round-to-nearest-even
__device__ __forceinline__ unsigned short f2bf(float f) {
    unsigned int u = __float_as_uint(f);
    unsigned int r = (u + 0x7FFFu + ((u >> 16) & 1u)) >> 16;
    return (unsigned short)r;
}

// async global->LDS, 16 B per lane; lds base must be wave-uniform, HW scatters
// lane i to base + i*16 (m97/m104 semantics).
__device__ __forceinline__ void load_lds16(const unsigned short* g, unsigned short* lds_base) {
    __builtin_amdgcn_global_load_lds(
        (const __attribute__((address_space(1))) unsigned int*)g,
        (__attribute__((address_space(3))) unsigned int*)lds_base, 16, 0, 0);
}

// ---------------------------------------------------------------------------
// Bulk fp32 -> bf16 convert (float4 in, short4 out). n4 = elem_count/4.
// ---------------------------------------------------------------------------
__global__ __launch_bounds__(256) void k_cvt(const float* __restrict__ src,
                                             unsigned short* __restrict__ dst, int n4) {
    int i = blockIdx.x * 256 + threadIdx.x;
    if (i >= n4) return;
    float4 v = ((const float4*)src)[i];
    short4v o;
    o[0] = (short)f2bf(v.x); o[1] = (short)f2bf(v.y);
    o[2] = (short)f2bf(v.z); o[3] = (short)f2bf(v.w);
    ((short4v*)dst)[i] = o;
}

// ---------------------------------------------------------------------------
// bias_sum[n] = bih[n] + bhh[n]
// ---------------------------------------------------------------------------
__global__ __launch_bounds__(256) void k_bias(const float* __restrict__ bih,
                                              const float* __restrict__ bhh,
                                              float* __restrict__ bs) {
    int i = blockIdx.x * 256 + threadIdx.x;
    if (i < G4) bs[i] = bih[i] + bhh[i];
}

// ---------------------------------------------------------------------------
// Embedding gather -> bf16, padding_idx(0) -> zeros. Xemb[m][k], m = t*128+b.
// ---------------------------------------------------------------------------
__global__ __launch_bounds__(256) void k_embed(const float* __restrict__ Wemb,
                                               const int* __restrict__ captions,
                                               unsigned short* __restrict__ Xemb) {
    int i = blockIdx.x * 256 + threadIdx.x;     // one thread per 4 elems
    if (i >= 3072 * 128) return;
    int row = i >> 7;                           // m = t*128 + b
    int k4  = i & 127;
    int b = row & 127, t = row >> 7;
    int tok = captions[b * T_ + t];
    short4v o = {0, 0, 0, 0};
    if (tok > 0 && tok < V_) {                  // tok==0 is padding -> zeros
        float4 v = ((const float4*)(Wemb + (long)tok * E_))[k4];
        o[0] = (short)f2bf(v.x); o[1] = (short)f2bf(v.y);
        o[2] = (short)f2bf(v.z); o[3] = (short)f2bf(v.w);
    }
    ((short4v*)Xemb)[(long)row * 128 + k4] = o;
}

// ---------------------------------------------------------------------------
// t=0 one-hot rows (fp32) + (captions_length - 1) tail
// ---------------------------------------------------------------------------
__global__ __launch_bounds__(256) void k_start(float* __restrict__ out,
                                               const int* __restrict__ cap_len) {
    int idx = blockIdx.x * 256 + threadIdx.x;
    constexpr int Q  = V_ / 4;                  // 2500 float4 per row
    constexpr int NQ = B_ * Q;                  // 320000
    float4 zero = {0.f, 0.f, 0.f, 0.f};
    float4 one1 = {0.f, 1.f, 0.f, 0.f};         // one-hot at v=1
    for (int i = idx; i < NQ; i += gridDim.x * 256) {
        int b = i / Q;
        int q = i - b * Q;
        ((float4*)out)[(long)b * (TP1 * V_ / 4) + q] = (q == 0) ? one1 : zero;
    }
    if (idx < B_) {
        out[(size_t)B_ * TP1 * V_ + idx] = (float)(cap_len[idx] - 1);
    }
}

// ---------------------------------------------------------------------------
// Fused LSTM step: GEMM (all 4 gate quadrants for this WG's h-slice) + cell.
// grid = 16 WGs x 512 thr: WG = (ms = bid&1 -> M half, hs = bid>>1 -> 64-wide
// h-slice). Wave w: quadrant q = w>>1, sub-col half sub = w&1; computes a
// 64(M) x 32(N) tile at n = q*512 + h0 + sub*32 via 4x2 MFMA 16x16x32, K=1024
// (Xemb_t then h_{t-1}). Gates exchanged via 64 KB LDS; cell applied in-block.
// h_t written to Hall[t] (read next step as h input: per-t slice => no race).
// ---------------------------------------------------------------------------
__global__ __launch_bounds__(512) void k_step(const unsigned short* __restrict__ Xt,
                                              const unsigned short* __restrict__ hprev,
                                              const unsigned short* __restrict__ Wih,
                                              const unsigned short* __restrict__ Whh,
                                              const float* __restrict__ bias_sum,
                                              float* __restrict__ cbuf,
                                              unsigned short* __restrict__ hout,
                                              int t) {
    __shared__ float Lg[4][64][64];             // 65536 B
    int w    = threadIdx.x >> 6;                // 0..7
    int lane = threadIdx.x & 63;
    int q = w >> 1, sub = w & 1;
    int ms = blockIdx.x & 1;
    int h0 = (blockIdx.x >> 1) * 64;
    int lm = lane & 15, lq = lane >> 4;
    int m_base = ms * 64;

    long arow[4];
    #pragma unroll
    for (int mi = 0; mi < 4; mi++) arow[mi] = (long)(m_base + mi * 16 + lm) * 512;
    long brow[2];
    #pragma unroll
    for (int ni = 0; ni < 2; ni++)
        brow[ni] = (long)(q * 512 + h0 + sub * 32 + ni * 16 + lm) * 512;

    const short* Axs = (const short*)Xt;
    const short* Ahs = (const short*)hprev;
    const short* Bis = (const short*)Wih;
    const short* Bhs = (const short*)Whh;

    f32x4 acc[4][2] = {};
    #pragma unroll
    for (int k0 = 0; k0 < 512; k0 += 32) {
        int ko = k0 + lq * 8;
        bf16x8 a[4], b[2];
        #pragma unroll
        for (int mi = 0; mi < 4; mi++) a[mi] = *(const bf16x8*)(Axs + arow[mi] + ko);
        #pragma unroll
        for (int ni = 0; ni < 2; ni++) b[ni] = *(const bf16x8*)(Bis + brow[ni] + ko);
        #pragma unroll
        for (int mi = 0; mi < 4; mi++)
            #pragma unroll
            for (int ni = 0; ni < 2; ni++)
                acc[mi][ni] = MFMA_16x16x32_BF16(a[mi], b[ni], acc[mi][ni]);
    }
    #pragma unroll
    for (int k0 = 0; k0 < 512; k0 += 32) {
        int ko = k0 + lq * 8;
        bf16x8 a[4], b[2];
        #pragma unroll
        for (int mi = 0; mi < 4; mi++) a[mi] = *(const bf16x8*)(Ahs + arow[mi] + ko);
        #pragma unroll
        for (int ni = 0; ni < 2; ni++) b[ni] = *(const bf16x8*)(Bhs + brow[ni] + ko);
        #pragma unroll
        for (int mi = 0; mi < 4; mi++)
            #pragma unroll
            for (int ni = 0; ni < 2; ni++)
                acc[mi][ni] = MFMA_16x16x32_BF16(a[mi], b[ni], acc[mi][ni]);
    }

    // gates -> LDS (with bias)
    #pragma unroll
    for (int mi = 0; mi < 4; mi++) {
        #pragma unroll
        for (int ni = 0; ni < 2; ni++) {
            int nl = sub * 32 + ni * 16 + lm;           // 0..63 in h-slice
            float bs = bias_sum[q * 512 + h0 + nl];
            #pragma unroll
            for (int r = 0; r < 4; r++)
                Lg[q][mi * 16 + lq * 4 + r][nl] = acc[mi][ni][r] + bs;
        }
    }
    __syncthreads();

    // cell: 512 threads x 8 elems = 64x64
    int ml = threadIdx.x >> 3;          // 0..63
    int c0 = (threadIdx.x & 7) * 8;
    int b = m_base + ml;
    #pragma unroll
    for (int j = 0; j < 8; j++) {
        int hl = c0 + j;
        int idx = b * 512 + h0 + hl;
        float gi = Lg[0][ml][hl];
        float gf = Lg[1][ml][hl];
        float gg = Lg[2][ml][hl];
        float go = Lg[3][ml][hl];
        float cprev = t ? cbuf[idx] : 0.f;
        float si = 1.f / (1.f + expf(-gi));
        float sf = 1.f / (1.f + expf(-gf));
        float so = 1.f / (1.f + expf(-go));
        float cn = sf * cprev + si * tanhf(gg);
        float hn = so * tanhf(cn);
        cbuf[idx] = cn;
        hout[idx] = f2bf(hn);
    }
}

// ---------------------------------------------------------------------------
// Logits: Hall[3072,512](bf16) @ Wout_bf^T + b_out -> fp32 out[b][t+1][v].
// 128x128 block tile (4 waves of 64x64), BK=64, single-buffered LDS staged via
// global_load_lds width=16 with XOR-swizzled chunks (conflict-free b128 reads).
// grid = 79(N) x 24(M) = 1896 blocks; consecutive blocks share the B-tile.
// ---------------------------------------------------------------------------
__global__ __launch_bounds__(256) void k_logits(const unsigned short* __restrict__ Hall,
                                                const unsigned short* __restrict__ Wout,
                                                const float* __restrict__ bout,
                                                float* __restrict__ out) {
    __shared__ unsigned short As[128 * 64];      // 16 KB, swizzled
    __shared__ unsigned short Bs[128 * 64];      // 16 KB, swizzled
    int bid  = blockIdx.x;
    int nt   = bid / 24;                         // 0..78
    int mt   = bid - nt * 24;                    // 0..23 (= t)
    int w    = threadIdx.x >> 6;                 // 0..3
    int lane = threadIdx.x & 63;
    int wm = w >> 1, wn = w & 1;                 // 2x2 waves of 64x64
    int lm = lane & 15, lq = lane >> 4;

    const unsigned short* Ab = Hall + (long)mt * 128 * 512;
    const unsigned short* Bb = Wout + (long)nt * 128 * 512;

    // per-lane staging source geometry (constant across K-iters except k0)
    int flat = w * 1024 + lane * 16;             // byte offset before r*4096
    f32x4 acc[4][4] = {};

    for (int kk = 0; kk < 8; kk++) {
        int k0 = kk * 64;
        __syncthreads();                         // LDS reuse guard
        #pragma unroll
        for (int r = 0; r < 4; r++) {
            int fo  = flat + r * 4096;
            int row = fo >> 7;                   // 0..127
            int p   = (fo >> 4) & 7;             // physical 16B chunk in row
            int kc  = p ^ (row & 7);             // global k-chunk (XOR swizzle)
            const unsigned short* ga = Ab + row * 512 + k0 + kc * 8;
            const unsigned short* gb = Bb + row * 512 + k0 + kc * 8;
            unsigned short* la = (unsigned short*)((char*)As + w * 1024 + r * 4096);
            unsigned short* lb = (unsigned short*)((char*)Bs + w * 1024 + r * 4096);
            load_lds16(ga, la);
            load_lds16(gb, lb);
        }
        __syncthreads();                         // drains vmcnt before barrier

        #pragma unroll
        for (int k2 = 0; k2 < 2; k2++) {
            bf16x8 af[4], bf[4];
            #pragma unroll
            for (int mi = 0; mi < 4; mi++) {
                int row = wm * 64 + mi * 16 + lm;
                int p = (k2 * 4 + lq) ^ (row & 7);
                af[mi] = *(const bf16x8*)((const char*)As + row * 128 + p * 16);
            }
            #pragma unroll
            for (int ni = 0; ni < 4; ni++) {
                int row = wn * 64 + ni * 16 + lm;
                int p = (k2 * 4 + lq) ^ (row & 7);
                bf[ni] = *(const bf16x8*)((const char*)Bs + row * 128 + p * 16);
            }
            #pragma unroll
            for (int mi = 0; mi < 4; mi++)
                #pragma unroll
                for (int ni = 0; ni < 4; ni++)
                    acc[mi][ni] = MFMA_16x16x32_BF16(af[mi], bf[ni], acc[mi][ni]);
        }
    }

    // epilogue
    float bo[4];
    #pragma unroll
    for (int ni = 0; ni < 4; ni++) {
        int n = nt * 128 + wn * 64 + ni * 16 + lm;
        bo[ni] = (n < V_) ? bout[n] : 0.f;
    }
    #pragma unroll
    for (int mi = 0; mi < 4; mi++) {
        #pragma unroll
        for (int r = 0; r < 4; r++) {
            int b = wm * 64 + mi * 16 + lq * 4 + r;   // batch (m-local); t = mt
            float* orow = out + ((size_t)b * TP1 + mt + 1) * V_;
            #pragma unroll
            for (int ni = 0; ni < 4; ni++) {
                int n = nt * 128 + wn * 64 + ni * 16 + lm;
                if (n < V_) orow[n] = acc[mi][ni][r] + bo[ni];
            }
        }
    }
}

// ---------------------------------------------------------------------------
extern "C" void kernel_launch(void* const* d_in, const int* in_sizes, int n_in,
                              void* d_out, int out_size, void* d_ws, size_t ws_size,
                              hipStream_t stream) {
    const float* images   = (const float*)d_in[0];
    const int*   captions = (const int*)d_in[1];
    const int*   cap_len  = (const int*)d_in[2];
    const float* Wemb     = (const float*)d_in[3];
    const float* Wih      = (const float*)d_in[4];
    const float* Whh      = (const float*)d_in[5];
    const float* bih      = (const float*)d_in[6];
    const float* bhh      = (const float*)d_in[7];
    const float* Wout     = (const float*)d_in[8];
    const float* bout     = (const float*)d_in[9];
    float* out = (float*)d_out;
    (void)ws_size;

    // workspace layout (21,241,856 B total; Round-5 used 22.2 MB OK)
    char* ws = (char*)d_ws;
    unsigned short* Wih_bf  = (unsigned short*)(ws);              //  2,097,152
    unsigned short* Whh_bf  = (unsigned short*)(ws + 2097152);    //  2,097,152
    unsigned short* Wout_bf = (unsigned short*)(ws + 4194304);    // 10,354,688 (VP_ rows; pad stays 0xAA = tiny finite bf16)
    unsigned short* Xemb    = (unsigned short*)(ws + 14548992);   //  3,145,728
    unsigned short* Hall    = (unsigned short*)(ws + 17694720);   //  3,145,728
    unsigned short* hbimg   = (unsigned short*)(ws + 20840448);   //    131,072
    float*          cbuf    = (float*)(ws + 20971520);            //    262,144
    float*          bsum    = (float*)(ws + 21233664);            //      8,192

    // staging
    k_cvt<<<1024, 256, 0, stream>>>(Wih,    Wih_bf,  G4 * E_ / 4);
    k_cvt<<<1024, 256, 0, stream>>>(Whh,    Whh_bf,  G4 * H_ / 4);
    k_cvt<<<5000, 256, 0, stream>>>(Wout,   Wout_bf, V_ * H_ / 4);
    k_cvt<<<  64, 256, 0, stream>>>(images, hbimg,   B_ * H_ / 4);
    k_embed<<<1536, 256, 0, stream>>>(Wemb, captions, Xemb);
    k_bias<<<8, 256, 0, stream>>>(bih, bhh, bsum);
    k_start<<<1250, 256, 0, stream>>>(out, cap_len);

    // fused serial recurrence: 24 launches, h chained through Hall slices
    for (int t = 0; t < T_; t++) {
        const unsigned short* hprev = (t == 0) ? hbimg : (Hall + (long)(t - 1) * B_ * H_);
        k_step<<<16, 512, 0, stream>>>(Xemb + (long)t * B_ * E_, hprev,
                                       Wih_bf, Whh_bf, bsum, cbuf,
                                       Hall + (long)t * B_ * H_, t);
    }

    // logits: 79 N-tiles x 24 M-tiles
    k_logits<<<79 * 24, 256, 0, stream>>>(Hall, Wout_bf, bout, out);
}

// Round 7
// 1043.596 us; speedup vs baseline: 1.3244x; 1.3244x over previous
//
#include <hip/hip_runtime.h>

// ---- problem constants ----
constexpr int B_  = 128;
constexpr int T_  = 24;
constexpr int E_  = 512;
constexpr int H_  = 512;
constexpr int V_  = 10000;
constexpr int VP_ = 10112;  // V padded to 128-multiple for logits tiling
constexpr int G4  = 2048;   // 4*H
constexpr int TP1 = 25;     // T+1

typedef __attribute__((ext_vector_type(8))) short bf16x8;   // 8 bf16 = 4 VGPR
typedef __attribute__((ext_vector_type(4))) short short4v;  // 4 bf16 = 8 B
typedef __attribute__((ext_vector_type(4))) float f32x4;

#define MFMA_16x16x32_BF16(a, b, c) __builtin_amdgcn_mfma_f32_16x16x32_bf16((a), (b), (c), 0, 0, 0)

// fp32 -> bf16 round-to-nearest-even
__device__ __forceinline__ unsigned short f2bf(float f) {
    unsigned int u = __float_as_uint(f);
    unsigned int r = (u + 0x7FFFu + ((u >> 16) & 1u)) >> 16;
    return (unsigned short)r;
}
__device__ __forceinline__ float bf2f(unsigned short s) {
    return __uint_as_float(((unsigned int)s) << 16);
}

// async global->LDS, 16 B per lane; lds base wave-uniform, HW scatters lane i
// to base + i*16 (m97/m104 semantics).
__device__ __forceinline__ void load_lds16(const unsigned short* g, unsigned short* lds_base) {
    __builtin_amdgcn_global_load_lds(
        (const __attribute__((address_space(1))) unsigned int*)g,
        (__attribute__((address_space(3))) unsigned int*)lds_base, 16, 0, 0);
}

// ---------------------------------------------------------------------------
// Bulk fp32 -> bf16 convert (float4 in, short4 out). n4 = elem_count/4.
// ---------------------------------------------------------------------------
__global__ __launch_bounds__(256) void k_cvt(const float* __restrict__ src,
                                             unsigned short* __restrict__ dst, int n4) {
    int i = blockIdx.x * 256 + threadIdx.x;
    if (i >= n4) return;
    float4 v = ((const float4*)src)[i];
    short4v o;
    o[0] = (short)f2bf(v.x); o[1] = (short)f2bf(v.y);
    o[2] = (short)f2bf(v.z); o[3] = (short)f2bf(v.w);
    ((short4v*)dst)[i] = o;
}

// ---------------------------------------------------------------------------
// bias_sum[n] = bih[n] + bhh[n]; also zeroes the barrier counter.
// ---------------------------------------------------------------------------
__global__ __launch_bounds__(256) void k_bias(const float* __restrict__ bih,
                                              const float* __restrict__ bhh,
                                              float* __restrict__ bs,
                                              int* __restrict__ cnt) {
    int i = blockIdx.x * 256 + threadIdx.x;
    if (i < G4) bs[i] = bih[i] + bhh[i];
    if (i == 0) *cnt = 0;
}

// ---------------------------------------------------------------------------
// Embedding gather -> bf16, padding_idx(0) -> zeros. Xemb[m][k], m = t*128+b.
// ---------------------------------------------------------------------------
__global__ __launch_bounds__(256) void k_embed(const float* __restrict__ Wemb,
                                               const int* __restrict__ captions,
                                               unsigned short* __restrict__ Xemb) {
    int i = blockIdx.x * 256 + threadIdx.x;     // one thread per 4 elems
    if (i >= 3072 * 128) return;
    int row = i >> 7;                           // m = t*128 + b
    int k4  = i & 127;
    int b = row & 127, t = row >> 7;
    int tok = captions[b * T_ + t];
    short4v o = {0, 0, 0, 0};
    if (tok > 0 && tok < V_) {                  // tok==0 is padding -> zeros
        float4 v = ((const float4*)(Wemb + (long)tok * E_))[k4];
        o[0] = (short)f2bf(v.x); o[1] = (short)f2bf(v.y);
        o[2] = (short)f2bf(v.z); o[3] = (short)f2bf(v.w);
    }
    ((short4v*)Xemb)[(long)row * 128 + k4] = o;
}

// ---------------------------------------------------------------------------
// t=0 one-hot rows (fp32) + (captions_length - 1) tail
// ---------------------------------------------------------------------------
__global__ __launch_bounds__(256) void k_start(float* __restrict__ out,
                                               const int* __restrict__ cap_len) {
    int idx = blockIdx.x * 256 + threadIdx.x;
    constexpr int Q  = V_ / 4;                  // 2500 float4 per row
    constexpr int NQ = B_ * Q;                  // 320000
    float4 zero = {0.f, 0.f, 0.f, 0.f};
    float4 one1 = {0.f, 1.f, 0.f, 0.f};         // one-hot at v=1
    for (int i = idx; i < NQ; i += gridDim.x * 256) {
        int b = i / Q;
        int q = i - b * Q;
        ((float4*)out)[(long)b * (TP1 * V_ / 4) + q] = (q == 0) ? one1 : zero;
    }
    if (idx < B_) {
        out[(size_t)B_ * TP1 * V_ + idx] = (float)(cap_len[idx] - 1);
    }
}

// ---------------------------------------------------------------------------
// Pregates: Xemb[3072,512](bf16) @ Wih^T + bias_sum -> bf16 pregates[m][n].
// Same LDS-tiled structure as k_logits. grid = 16(N) x 24(M) = 384 blocks.
// ---------------------------------------------------------------------------
__global__ __launch_bounds__(256) void k_pregate(const unsigned short* __restrict__ Xemb,
                                                 const unsigned short* __restrict__ Wih,
                                                 const float* __restrict__ bsum,
                                                 unsigned short* __restrict__ pregates) {
    __shared__ unsigned short As[128 * 64];      // 16 KB, swizzled
    __shared__ unsigned short Bs[128 * 64];      // 16 KB, swizzled
    int bid  = blockIdx.x;
    int nt   = bid / 24;                         // 0..15
    int mt   = bid - nt * 24;                    // 0..23
    int w    = threadIdx.x >> 6;                 // 0..3
    int lane = threadIdx.x & 63;
    int wm = w >> 1, wn = w & 1;
    int lm = lane & 15, lq = lane >> 4;

    const unsigned short* Ab = Xemb + (long)mt * 128 * 512;
    const unsigned short* Bb = Wih  + (long)nt * 128 * 512;

    int flat = w * 1024 + lane * 16;
    f32x4 acc[4][4] = {};

    for (int kk = 0; kk < 8; kk++) {
        int k0 = kk * 64;
        __syncthreads();
        #pragma unroll
        for (int r = 0; r < 4; r++) {
            int fo  = flat + r * 4096;
            int row = fo >> 7;
            int p   = (fo >> 4) & 7;
            int kc  = p ^ (row & 7);
            load_lds16(Ab + row * 512 + k0 + kc * 8,
                       (unsigned short*)((char*)As + w * 1024 + r * 4096));
            load_lds16(Bb + row * 512 + k0 + kc * 8,
                       (unsigned short*)((char*)Bs + w * 1024 + r * 4096));
        }
        __syncthreads();

        #pragma unroll
        for (int k2 = 0; k2 < 2; k2++) {
            bf16x8 af[4], bf[4];
            #pragma unroll
            for (int mi = 0; mi < 4; mi++) {
                int row = wm * 64 + mi * 16 + lm;
                int p = (k2 * 4 + lq) ^ (row & 7);
                af[mi] = *(const bf16x8*)((const char*)As + row * 128 + p * 16);
            }
            #pragma unroll
            for (int ni = 0; ni < 4; ni++) {
                int row = wn * 64 + ni * 16 + lm;
                int p = (k2 * 4 + lq) ^ (row & 7);
                bf[ni] = *(const bf16x8*)((const char*)Bs + row * 128 + p * 16);
            }
            #pragma unroll
            for (int mi = 0; mi < 4; mi++)
                #pragma unroll
                for (int ni = 0; ni < 4; ni++)
                    acc[mi][ni] = MFMA_16x16x32_BF16(af[mi], bf[ni], acc[mi][ni]);
        }
    }

    #pragma unroll
    for (int mi = 0; mi < 4; mi++) {
        #pragma unroll
        for (int r = 0; r < 4; r++) {
            int m = mt * 128 + wm * 64 + mi * 16 + lq * 4 + r;
            #pragma unroll
            for (int ni = 0; ni < 4; ni++) {
                int n = nt * 128 + wn * 64 + ni * 16 + lm;
                pregates[(long)m * G4 + n] = f2bf(acc[mi][ni][r] + bsum[n]);
            }
        }
    }
}

// ---------------------------------------------------------------------------
// Persistent LSTM recurrence: 32 WGs x 512 threads, all 24 steps in one
// launch. WG w owns h-columns [16w,16w+16). Whh fragments register-resident
// across steps (16 x bf16x8/lane); c-state in registers; gates exchanged via
// padded LDS; h chained through Hall[t] with a device-scope atomic barrier.
// ---------------------------------------------------------------------------
__global__ __launch_bounds__(512) void k_lstm(const unsigned short* __restrict__ hb0,
                                              unsigned short* __restrict__ Hall,
                                              const unsigned short* __restrict__ Whh,
                                              const unsigned short* __restrict__ pregates,
                                              int* __restrict__ cnt) {
    __shared__ float Lg[4][128][17];             // 34,816 B (pad 17 kills conflicts)
    int w    = blockIdx.x;                       // 0..31 : h-slice
    int wv   = threadIdx.x >> 6;                 // 0..7
    int lane = threadIdx.x & 63;
    int q  = wv >> 1, mh = wv & 1;               // gate quadrant, M half
    int lm = lane & 15, lq = lane >> 4;
    int n  = q * 512 + w * 16 + lm;              // Whh row this lane holds

    // Whh fragments for all K, loaded once, live in registers for all steps
    bf16x8 bfrag[16];
    {
        const short* Brow = (const short*)Whh + (long)n * 512;
        #pragma unroll
        for (int k = 0; k < 16; k++)
            bfrag[k] = *(const bf16x8*)(Brow + k * 32 + lq * 8);
    }

    // cell-thread mapping: thread owns (batch cb, h-cols cj..cj+3); c in regs
    int cb = threadIdx.x >> 2;                   // 0..127
    int cj = (threadIdx.x & 3) * 4;              // 0,4,8,12
    float creg[4] = {0.f, 0.f, 0.f, 0.f};

    for (int t = 0; t < T_; t++) {
        const short* Ah = (const short*)((t == 0) ? hb0 : (Hall + (long)(t - 1) * B_ * H_));

        f32x4 acc[4] = {};
        #pragma unroll
        for (int k = 0; k < 16; k++) {
            int ko = k * 32 + lq * 8;
            #pragma unroll
            for (int mi = 0; mi < 4; mi++) {
                bf16x8 a = *(const bf16x8*)(Ah + (long)(mh * 64 + mi * 16 + lm) * 512 + ko);
                acc[mi] = MFMA_16x16x32_BF16(a, bfrag[k], acc[mi]);
            }
        }

        // add pregate (bias already folded in), publish to LDS
        const unsigned short* pg = pregates + (long)t * B_ * G4;
        #pragma unroll
        for (int mi = 0; mi < 4; mi++) {
            #pragma unroll
            for (int r = 0; r < 4; r++) {
                int m = mh * 64 + mi * 16 + lq * 4 + r;
                Lg[q][m][lm] = acc[mi][r] + bf2f(pg[(long)m * G4 + n]);
            }
        }
        __syncthreads();

        // cell for this WG's 16 h-columns x 128 batches
        unsigned short* Ht = Hall + (long)t * B_ * H_;
        short4v hv;
        #pragma unroll
        for (int i = 0; i < 4; i++) {
            int hl = cj + i;
            float gi = Lg[0][cb][hl];
            float gf = Lg[1][cb][hl];
            float gg = Lg[2][cb][hl];
            float go = Lg[3][cb][hl];
            float si = 1.f / (1.f + expf(-gi));
            float sf = 1.f / (1.f + expf(-gf));
            float so = 1.f / (1.f + expf(-go));
            float cn = sf * creg[i] + si * tanhf(gg);
            creg[i] = cn;
            hv[i] = (short)f2bf(so * tanhf(cn));
        }
        *(short4v*)(Ht + cb * H_ + w * 16 + cj) = hv;

        // device-scope barrier: h of step t visible to all WGs before t+1
        __threadfence();
        __syncthreads();                         // all WG writes + Lg reads done
        if (threadIdx.x == 0) {
            atomicAdd(cnt, 1);
            while (atomicAdd(cnt, 0) < 32 * (t + 1)) {}
        }
        __syncthreads();
        __threadfence();                         // acquire: invalidate stale lines
    }
}

// ---------------------------------------------------------------------------
// Logits: Hall[3072,512](bf16) @ Wout_bf^T + b_out -> fp32 out[b][t+1][v].
// 128x128 block tile, BK=64, XOR-swizzled LDS, global_load_lds width=16.
// ---------------------------------------------------------------------------
__global__ __launch_bounds__(256) void k_logits(const unsigned short* __restrict__ Hall,
                                                const unsigned short* __restrict__ Wout,
                                                const float* __restrict__ bout,
                                                float* __restrict__ out) {
    __shared__ unsigned short As[128 * 64];      // 16 KB, swizzled
    __shared__ unsigned short Bs[128 * 64];      // 16 KB, swizzled
    int bid  = blockIdx.x;
    int nt   = bid / 24;                         // 0..78
    int mt   = bid - nt * 24;                    // 0..23 (= t)
    int w    = threadIdx.x >> 6;                 // 0..3
    int lane = threadIdx.x & 63;
    int wm = w >> 1, wn = w & 1;
    int lm = lane & 15, lq = lane >> 4;

    const unsigned short* Ab = Hall + (long)mt * 128 * 512;
    const unsigned short* Bb = Wout + (long)nt * 128 * 512;

    int flat = w * 1024 + lane * 16;
    f32x4 acc[4][4] = {};

    for (int kk = 0; kk < 8; kk++) {
        int k0 = kk * 64;
        __syncthreads();
        #pragma unroll
        for (int r = 0; r < 4; r++) {
            int fo  = flat + r * 4096;
            int row = fo >> 7;
            int p   = (fo >> 4) & 7;
            int kc  = p ^ (row & 7);
            load_lds16(Ab + row * 512 + k0 + kc * 8,
                       (unsigned short*)((char*)As + w * 1024 + r * 4096));
            load_lds16(Bb + row * 512 + k0 + kc * 8,
                       (unsigned short*)((char*)Bs + w * 1024 + r * 4096));
        }
        __syncthreads();

        #pragma unroll
        for (int k2 = 0; k2 < 2; k2++) {
            bf16x8 af[4], bf[4];
            #pragma unroll
            for (int mi = 0; mi < 4; mi++) {
                int row = wm * 64 + mi * 16 + lm;
                int p = (k2 * 4 + lq) ^ (row & 7);
                af[mi] = *(const bf16x8*)((const char*)As + row * 128 + p * 16);
            }
            #pragma unroll
            for (int ni = 0; ni < 4; ni++) {
                int row = wn * 64 + ni * 16 + lm;
                int p = (k2 * 4 + lq) ^ (row & 7);
                bf[ni] = *(const bf16x8*)((const char*)Bs + row * 128 + p * 16);
            }
            #pragma unroll
            for (int mi = 0; mi < 4; mi++)
                #pragma unroll
                for (int ni = 0; ni < 4; ni++)
                    acc[mi][ni] = MFMA_16x16x32_BF16(af[mi], bf[ni], acc[mi][ni]);
        }
    }

    float bo[4];
    #pragma unroll
    for (int ni = 0; ni < 4; ni++) {
        int n = nt * 128 + wn * 64 + ni * 16 + lm;
        bo[ni] = (n < V_) ? bout[n] : 0.f;
    }
    #pragma unroll
    for (int mi = 0; mi < 4; mi++) {
        #pragma unroll
        for (int r = 0; r < 4; r++) {
            int b = wm * 64 + mi * 16 + lq * 4 + r;   // batch; t = mt
            float* orow = out + ((size_t)b * TP1 + mt + 1) * V_;
            #pragma unroll
            for (int ni = 0; ni < 4; ni++) {
                int n = nt * 128 + wn * 64 + ni * 16 + lm;
                if (n < V_) orow[n] = acc[mi][ni][r] + bo[ni];
            }
        }
    }
}

// ---------------------------------------------------------------------------
extern "C" void kernel_launch(void* const* d_in, const int* in_sizes, int n_in,
                              void* d_out, int out_size, void* d_ws, size_t ws_size,
                              hipStream_t stream) {
    const float* images   = (const float*)d_in[0];
    const int*   captions = (const int*)d_in[1];
    const int*   cap_len  = (const int*)d_in[2];
    const float* Wemb     = (const float*)d_in[3];
    const float* Wih      = (const float*)d_in[4];
    const float* Whh      = (const float*)d_in[5];
    const float* bih      = (const float*)d_in[6];
    const float* bhh      = (const float*)d_in[7];
    const float* Wout     = (const float*)d_in[8];
    const float* bout     = (const float*)d_in[9];
    float* out = (float*)d_out;
    (void)ws_size;

    // workspace layout (33,562,880 B total)
    char* ws = (char*)d_ws;
    unsigned short* Wih_bf   = (unsigned short*)(ws);              //  2,097,152
    unsigned short* Whh_bf   = (unsigned short*)(ws + 2097152);    //  2,097,152
    unsigned short* Wout_bf  = (unsigned short*)(ws + 4194304);    // 10,354,688 (VP_ rows)
    unsigned short* Xemb     = (unsigned short*)(ws + 14548992);   //  3,145,728
    unsigned short* Hall     = (unsigned short*)(ws + 17694720);   //  3,145,728
    unsigned short* hbimg    = (unsigned short*)(ws + 20840448);   //    131,072
    float*          bsum     = (float*)(ws + 20971520);            //      8,192
    int*            cnt      = (int*)(ws + 20979712);              //        256
    unsigned short* pregates = (unsigned short*)(ws + 20979968);   // 12,582,912

    // staging (parallel, order-independent among themselves)
    k_cvt<<<1024, 256, 0, stream>>>(Wih,    Wih_bf,  G4 * E_ / 4);
    k_cvt<<<1024, 256, 0, stream>>>(Whh,    Whh_bf,  G4 * H_ / 4);
    k_cvt<<<5000, 256, 0, stream>>>(Wout,   Wout_bf, V_ * H_ / 4);
    k_cvt<<<  64, 256, 0, stream>>>(images, hbimg,   B_ * H_ / 4);
    k_embed<<<1536, 256, 0, stream>>>(Wemb, captions, Xemb);
    k_bias<<<8, 256, 0, stream>>>(bih, bhh, bsum, cnt);
    k_start<<<1250, 256, 0, stream>>>(out, cap_len);

    // pregates = Xemb @ Wih^T + bias (parallel GEMM, bf16 out)
    k_pregate<<<16 * 24, 256, 0, stream>>>(Xemb, Wih_bf, bsum, pregates);

    // entire recurrence in ONE persistent launch
    k_lstm<<<32, 512, 0, stream>>>(hbimg, Hall, Whh_bf, pregates, cnt);

    // logits: 79 N-tiles x 24 M-tiles
    k_logits<<<79 * 24, 256, 0, stream>>>(Hall, Wout_bf, bout, out);
}